// Round 15
// baseline (971.143 us; speedup 1.0000x reference)
//
#include <hip/hip_runtime.h>
#include <cstdint>
#include <cstddef>

#define B_  64
#define T_  512
#define S_  512
#define D_  256

#define GROUPS 16
#define BPG    16

typedef __attribute__((ext_vector_type(4))) float f32x4;
typedef __attribute__((ext_vector_type(8))) short bf16x8;

union UBF { bf16x8 v; uint32_t u[4]; };
union USH { bf16x8 v; ushort s[8]; };

// ---- helpers ----
__device__ __forceinline__ ushort f2bf(float f) {
    union { float f; uint32_t u; } v; v.f = f;
    uint32_t r = v.u + 0x7FFFu + ((v.u >> 16) & 1u);
    return (ushort)(r >> 16);
}
__device__ __forceinline__ float bf2f(ushort h) {
    union { uint32_t u; float f; } v; v.u = ((uint32_t)h) << 16; return v.f;
}
__device__ __forceinline__ uint4 ldx4u_cg(const uint32_t* p) {
    uint4 r;
    asm volatile("global_load_dwordx4 %0, %1, off sc0 sc1\n\ts_waitcnt vmcnt(0)"
                 : "=v"(r) : "v"(p) : "memory");
    return r;
}
__device__ __forceinline__ void st_cg_u32(uint32_t* p, uint32_t v) {
    asm volatile("global_store_dword %0, %1, off sc0 sc1" :: "v"(p), "v"(v) : "memory");
}
// out = [hi16(b) : hi16(a)]  (a = even k, b = odd k)
__device__ __forceinline__ uint32_t hi2(uint32_t a, uint32_t b) {
    return __builtin_amdgcn_perm(b, a, 0x07060302u);
}

// hbuf ring: 2 slots x 16384 u32 ([slot][b][d]); word = bf16(h)<<16 | step
// init 0xFFFFFFFF (step field 0xFFFF never matches t <= 510)
__global__ __launch_bounds__(256) void ws_init(uint32_t* __restrict__ hbuf) {
    int i = blockIdx.x * 256 + threadIdx.x;
    if (i < 2 * 16384)
        __hip_atomic_store(hbuf + i, 0xFFFFFFFFu, __ATOMIC_RELAXED, __HIP_MEMORY_SCOPE_AGENT);
}

// ==================== LSTM: in-lane combine MFMA ====================
// R11 verbatim (verified 3x: lstm=866us, absmax 0.015625) with ONE change:
// hlds double-buffered by step parity -> the trailing __syncthreads() is
// removed. Safety: a wave writes buffer t&1 again only at step t+2, after
// passing barrier t+1, which every wave reaches only after completing its
// step-t MFMA reads of buffer t&1. Poll is R11's simple vmcnt(0) load.

__global__ __launch_bounds__(256, 1) void lstm_persistent(
    const float* __restrict__ de,  const float* __restrict__ h0,
    const float* __restrict__ c0,
    const float* __restrict__ Wih, const float* __restrict__ Whh,
    const float* __restrict__ bih, const float* __restrict__ bhh,
    float* __restrict__ out, uint32_t* __restrict__ hbuf)
{
    __shared__ uint32_t hlds[2][4 * 260];  // packed h, double-buffered
    __shared__ float    glds[256];         // t=0 gates [gate][dim16][b]
    __shared__ float    t0buf[2][4][256];  // e0, h0

    const int tid = threadIdx.x;
    const int grp = blockIdx.x >> 4;
    const int jb  = blockIdx.x & 15;

    const int w  = tid >> 6;    // wave 0..3 (4 dims each)
    const int l  = tid & 63;
    const int lr = l & 15;
    const int lg = l >> 4;

    const int bl = lr & 3;
    const int bx = grp * 4 + bl;
    const int dx = jb * 16 + w * 4 + lg;
    const bool store_lane = (lr < 4);

    const float bs0 = bih[      dx] + bhh[      dx];
    const float bs1 = bih[256 + dx] + bhh[256 + dx];
    const float bs2 = bih[512 + dx] + bhh[512 + dx];
    const float bs3 = bih[768 + dx] + bhh[768 + dx];
    float c_reg = c0[(size_t)bx * 256 + dx];

    bf16x8 Ahi[8], Alo[8];

    // ---- t = 0: stage e0/h0, scalar dot into glds (verbatim R11) ----
    #pragma unroll
    for (int m = 0; m < 8; ++m) {
        int idx = m * 256 + tid;
        int arr = idx >> 10, bq = (idx >> 8) & 3, k = idx & 255;
        t0buf[arr][bq][k] = arr ? h0[(size_t)(grp * 4 + bq) * 256 + k]
                                : de[(size_t)(grp * 4 + bq) * T_ * D_ + k];
    }
    __syncthreads();
    {
        int r = tid >> 2, bq = tid & 3;
        int gr = (r >> 4) * 256 + jb * 16 + (r & 15);
        const float4* wi4 = (const float4*)(Wih + (size_t)gr * 256);
        const float4* wh4 = (const float4*)(Whh + (size_t)gr * 256);
        const float4* e4  = (const float4*)(&t0buf[0][bq][0]);
        const float4* h4  = (const float4*)(&t0buf[1][bq][0]);
        float a0 = 0.f, a1 = 0.f, a2 = 0.f, a3 = 0.f;
        #pragma unroll 8
        for (int k4 = 0; k4 < 64; ++k4) {
            float4 x = wi4[k4], y = e4[k4];
            a0 += x.x*y.x; a1 += x.y*y.y; a2 += x.z*y.z; a3 += x.w*y.w;
            x = wh4[k4]; y = h4[k4];
            a0 += x.x*y.x; a1 += x.y*y.y; a2 += x.z*y.z; a3 += x.w*y.w;
        }
        glds[(r >> 4) * 64 + (r & 15) * 4 + bq] = (a0 + a1) + (a2 + a3);
    }
    __syncthreads();

    // ---- t = 0 epilogue (in-lane binding, verbatim R11) ----
    {
        int d16 = w * 4 + lg;
        float gi = glds[      d16 * 4 + bl] + bs0;
        float gf = glds[ 64 + d16 * 4 + bl] + bs1;
        float gg = glds[128 + d16 * 4 + bl] + bs2;
        float go = glds[192 + d16 * 4 + bl] + bs3;
        float si = 1.f / (1.f + __expf(-gi));
        float sf = 1.f / (1.f + __expf(-gf));
        float so = 1.f / (1.f + __expf(-go));
        float tg = 1.f - 2.f / (1.f + __expf(2.f * gg));
        c_reg = sf * c_reg + si * tg;
        float tc = 1.f - 2.f / (1.f + __expf(2.f * c_reg));
        float hn = so * tc;
        if (store_lane) {
            uint32_t pk = ((uint32_t)f2bf(hn) << 16);   // t = 0
            st_cg_u32(hbuf + 0 * 16384 + grp * 1024 + bl * 256 + dx, pk);
            out[((size_t)bx * T_ + 0) * 512 + dx] = hn;
        }
    }

    // ---- one-time: Wc hi/lo A-frags (in-lane row binding, verbatim R11) ----
    {
        int gr = (lr & 3) * 256 + jb * 16 + w * 4 + (lr >> 2);
        const float4* wi4 = (const float4*)(Wih + (size_t)gr * 256);
        const float4* wh4 = (const float4*)(Whh + (size_t)gr * 256);
        #pragma unroll
        for (int kt = 0; kt < 8; ++kt) {
            float4 p  = wi4[kt * 8 + lg * 2], q  = wi4[kt * 8 + lg * 2 + 1];
            float4 r4 = wh4[kt * 8 + lg * 2], s4 = wh4[kt * 8 + lg * 2 + 1];
            float f[8] = {p.x + r4.x, p.y + r4.y, p.z + r4.z, p.w + r4.w,
                          q.x + s4.x, q.y + s4.y, q.z + s4.z, q.w + s4.w};
            USH hi, lo;
            #pragma unroll
            for (int j = 0; j < 8; ++j) {
                ushort h = f2bf(f[j]);
                hi.s[j] = h;
                lo.s[j] = f2bf(f[j] - bf2f(h));
            }
            Ahi[kt] = hi.v; Alo[kt] = lo.v;
        }
    }

    // ---- steady state ----
    for (int t = 1; t < T_; ++t) {
        // poll h_{t-1} (verbatim R11: simple vmcnt(0) load)
        const uint32_t expc = (uint32_t)(t - 1);
        const uint32_t* hp = hbuf + ((t - 1) & 1) * 16384 + grp * 1024 + tid * 4;
        uint4 v = ldx4u_cg(hp);
        while ((((v.x ^ expc) | (v.y ^ expc) | (v.z ^ expc) | (v.w ^ expc)) & 0xFFFFu) != 0u)
            v = ldx4u_cg(hp);
        *(uint4*)(&hlds[t & 1][0] + (tid >> 6) * 260 + (tid & 63) * 4) = v;
        __syncthreads();

        // B-frags via v_perm + dual-acc MFMA (verbatim R11)
        f32x4 acch = (f32x4){0.f, 0.f, 0.f, 0.f};
        f32x4 accl = (f32x4){0.f, 0.f, 0.f, 0.f};
        const uint32_t* hrow = &hlds[t & 1][0] + (lr & 3) * 260 + lg * 8;
        #pragma unroll
        for (int kt = 0; kt < 8; ++kt) {
            uint4 q0 = *(const uint4*)(hrow + kt * 32);
            uint4 q1 = *(const uint4*)(hrow + kt * 32 + 4);
            UBF bb;
            bb.u[0] = hi2(q0.x, q0.y);
            bb.u[1] = hi2(q0.z, q0.w);
            bb.u[2] = hi2(q1.x, q1.y);
            bb.u[3] = hi2(q1.z, q1.w);
            acch = __builtin_amdgcn_mfma_f32_16x16x32_bf16(Ahi[kt], bb.v, acch, 0, 0, 0);
            accl = __builtin_amdgcn_mfma_f32_16x16x32_bf16(Alo[kt], bb.v, accl, 0, 0, 0);
        }
        f32x4 acc = acch + accl;

        // in-lane epilogue (verbatim R11)
        {
            float gi = acc[0] + bs0, gf = acc[1] + bs1;
            float gg = acc[2] + bs2, go = acc[3] + bs3;
            float si = 1.f / (1.f + __expf(-gi));
            float sf = 1.f / (1.f + __expf(-gf));
            float so = 1.f / (1.f + __expf(-go));
            float tg = 1.f - 2.f / (1.f + __expf(2.f * gg));
            c_reg = sf * c_reg + si * tg;
            float tc = 1.f - 2.f / (1.f + __expf(2.f * c_reg));
            float hn = so * tc;
            if (store_lane) {
                if (t < T_ - 1) {
                    uint32_t pk = ((uint32_t)f2bf(hn) << 16) | (uint32_t)t;
                    st_cg_u32(hbuf + (t & 1) * 16384 + grp * 1024 + bl * 256 + dx, pk);
                }
                out[((size_t)bx * T_ + t) * 512 + dx] = hn;
            }
        }
        // no trailing barrier: next step writes the OTHER hlds buffer, and
        // buffer t&1 is rewritten only after barrier t+1 (see header comment)
    }
}

// ==================== Attention: bf16 MFMA flash (unchanged, verified) ========

__global__ __launch_bounds__(256, 2) void attn_kernel(
    const float* __restrict__ E, float* __restrict__ out)
{
    __shared__ alignas(16) ushort Ech [32 * 264];
    __shared__ alignas(16) ushort EchT[256 * 40];
    __shared__ alignas(16) ushort Phi[4][16 * 40];
    __shared__ alignas(16) ushort Plo[4][16 * 40];

    const int id  = blockIdx.x;
    const int xcd = id & 7, rr = id >> 3;
    const int tt  = rr & 7,  bh = rr >> 3;
    const int b   = bh * 8 + xcd;
    const int t0  = tt * 64;

    const int tid = threadIdx.x;
    const int w   = tid >> 6;
    const int l   = tid & 63;
    const int lr  = l & 15;
    const int lg  = l >> 4;

    bf16x8 Ahi[8], Alo[8];
    {
        const float* Hrow = out + ((size_t)b * T_ + (t0 + w * 16 + lr)) * 512;
        #pragma unroll
        for (int kt = 0; kt < 8; ++kt) {
            float4 x0 = *(const float4*)(Hrow + kt * 32 + lg * 8);
            float4 x1 = *(const float4*)(Hrow + kt * 32 + lg * 8 + 4);
            float f[8] = {x0.x, x0.y, x0.z, x0.w, x1.x, x1.y, x1.z, x1.w};
            USH hi, lo;
            #pragma unroll
            for (int j = 0; j < 8; ++j) {
                ushort h = f2bf(f[j]);
                hi.s[j] = h;
                lo.s[j] = f2bf(f[j] - bf2f(h));
            }
            Ahi[kt] = hi.v; Alo[kt] = lo.v;
        }
    }

    f32x4 ctx[16];
    #pragma unroll
    for (int i = 0; i < 16; ++i) ctx[i] = (f32x4){0.f, 0.f, 0.f, 0.f};
    float mrow[4] = {-1e30f, -1e30f, -1e30f, -1e30f};
    float srow[4] = {0.f, 0.f, 0.f, 0.f};

    const float* Eb = E + (size_t)b * S_ * 256;

    for (int c = 0; c < 16; ++c) {
        #pragma unroll
        for (int m = 0; m < 8; ++m) {
            int idx = m * 256 + tid;
            int sr = idx >> 6, k4 = idx & 63;
            float4 e = *(const float4*)(Eb + (size_t)(c * 32 + sr) * 256 + 4 * k4);
            ushort4 u;
            u.x = f2bf(e.x); u.y = f2bf(e.y); u.z = f2bf(e.z); u.w = f2bf(e.w);
            *(ushort4*)(&Ech[sr * 264 + 4 * k4]) = u;
        }
        __syncthreads();

        f32x4 sacc0 = (f32x4){0.f,0.f,0.f,0.f};
        f32x4 sacc1 = (f32x4){0.f,0.f,0.f,0.f};
        #pragma unroll
        for (int kt = 0; kt < 8; ++kt) {
            bf16x8 Bf0 = *(const bf16x8*)(&Ech[(0 * 16 + lr) * 264 + kt * 32 + lg * 8]);
            bf16x8 Bf1 = *(const bf16x8*)(&Ech[(1 * 16 + lr) * 264 + kt * 32 + lg * 8]);
            sacc0 = __builtin_amdgcn_mfma_f32_16x16x32_bf16(Ahi[kt], Bf0, sacc0, 0, 0, 0);
            sacc0 = __builtin_amdgcn_mfma_f32_16x16x32_bf16(Alo[kt], Bf0, sacc0, 0, 0, 0);
            sacc1 = __builtin_amdgcn_mfma_f32_16x16x32_bf16(Ahi[kt], Bf1, sacc1, 0, 0, 0);
            sacc1 = __builtin_amdgcn_mfma_f32_16x16x32_bf16(Alo[kt], Bf1, sacc1, 0, 0, 0);
        }

        #pragma unroll
        for (int m = 0; m < 8; ++m) {
            int idx = m * 256 + tid;
            int s = idx & 31, kq = idx >> 5;
            ushort4 v = *(const ushort4*)(&Ech[s * 264 + 4 * kq]);
            EchT[(4 * kq + 0) * 40 + s] = v.x;
            EchT[(4 * kq + 1) * 40 + s] = v.y;
            EchT[(4 * kq + 2) * 40 + s] = v.z;
            EchT[(4 * kq + 3) * 40 + s] = v.w;
        }

        float cmax[4], p0[4], p1[4], csum[4], mnew[4], scale[4];
        #pragma unroll
        for (int g = 0; g < 4; ++g) cmax[g] = fmaxf(sacc0[g], sacc1[g]);
        #pragma unroll
        for (int d = 1; d < 16; d <<= 1) {
            #pragma unroll
            for (int g = 0; g < 4; ++g) cmax[g] = fmaxf(cmax[g], __shfl_xor(cmax[g], d));
        }
        #pragma unroll
        for (int g = 0; g < 4; ++g) {
            mnew[g]  = fmaxf(mrow[g], cmax[g]);
            scale[g] = __expf(mrow[g] - mnew[g]);
            p0[g] = __expf(sacc0[g] - mnew[g]);
            p1[g] = __expf(sacc1[g] - mnew[g]);
            csum[g] = p0[g] + p1[g];
        }
        #pragma unroll
        for (int d = 1; d < 16; d <<= 1) {
            #pragma unroll
            for (int g = 0; g < 4; ++g) csum[g] += __shfl_xor(csum[g], d);
        }
        #pragma unroll
        for (int g = 0; g < 4; ++g) {
            srow[g] = srow[g] * scale[g] + csum[g];
            mrow[g] = mnew[g];
        }
        #pragma unroll
        for (int i = 0; i < 16; ++i) {
            ctx[i][0] *= scale[0]; ctx[i][1] *= scale[1];
            ctx[i][2] *= scale[2]; ctx[i][3] *= scale[3];
        }
        #pragma unroll
        for (int g = 0; g < 4; ++g) {
            int rrw = (lg * 4 + g) * 40;
            ushort h0v = f2bf(p0[g]);
            Phi[w][rrw + lr]      = h0v;
            Plo[w][rrw + lr]      = f2bf(p0[g] - bf2f(h0v));
            ushort h1v = f2bf(p1[g]);
            Phi[w][rrw + 16 + lr] = h1v;
            Plo[w][rrw + 16 + lr] = f2bf(p1[g] - bf2f(h1v));
        }
        __syncthreads();

        {
            bf16x8 Ap = *(const bf16x8*)(&Phi[w][lr * 40 + lg * 8]);
            bf16x8 Aq = *(const bf16x8*)(&Plo[w][lr * 40 + lg * 8]);
            #pragma unroll
            for (int dt = 0; dt < 16; ++dt) {
                bf16x8 Bf = *(const bf16x8*)(&EchT[(dt * 16 + lr) * 40 + lg * 8]);
                ctx[dt] = __builtin_amdgcn_mfma_f32_16x16x32_bf16(Ap, Bf, ctx[dt], 0, 0, 0);
                ctx[dt] = __builtin_amdgcn_mfma_f32_16x16x32_bf16(Aq, Bf, ctx[dt], 0, 0, 0);
            }
        }
        __syncthreads();
    }

    float inv[4];
    #pragma unroll
    for (int g = 0; g < 4; ++g) inv[g] = 1.f / srow[g];
    #pragma unroll
    for (int dt = 0; dt < 16; ++dt) {
        #pragma unroll
        for (int g = 0; g < 4; ++g) {
            out[((size_t)b * T_ + (t0 + w * 16 + lg * 4 + g)) * 512 + 256 + dt * 16 + lr] =
                ctx[dt][g] * inv[g];
        }
    }
}

// -------------------- launch --------------------

extern "C" void kernel_launch(void* const* d_in, const int* in_sizes, int n_in,
                              void* d_out, int out_size, void* d_ws, size_t ws_size,
                              hipStream_t stream)
{
    const float* de  = (const float*)d_in[0];
    const float* h0  = (const float*)d_in[1];
    const float* c0  = (const float*)d_in[2];
    const float* E   = (const float*)d_in[3];
    const float* Wih = (const float*)d_in[4];
    const float* Whh = (const float*)d_in[5];
    const float* bih = (const float*)d_in[6];
    const float* bhh = (const float*)d_in[7];
    float* out  = (float*)d_out;
    uint32_t* hbuf = (uint32_t*)d_ws;

    ws_init<<<128, 256, 0, stream>>>(hbuf);

    void* args[] = {(void*)&de, (void*)&h0, (void*)&c0, (void*)&Wih, (void*)&Whh,
                    (void*)&bih, (void*)&bhh, (void*)&out, (void*)&hbuf};
    hipLaunchCooperativeKernel((const void*)lstm_persistent,
                               dim3(GROUPS * BPG), dim3(256), args, 0, stream);

    attn_kernel<<<dim3(512), 256, 0, stream>>>(E, out);
}